// Round 15
// baseline (500.725 us; speedup 1.0000x reference)
//
#include <hip/hip_runtime.h>
#include <hip/hip_fp16.h>

#define N_NODES 30000
#define N_EDGES 480000
#define NB 64           // blocks per etype for counting sort
#define CHUNK 7500      // N_EDGES / NB  (< 65536 so u16 ranks/counts are safe)

typedef _Float16 f16;
typedef f16 f16x8 __attribute__((ext_vector_type(8)));
typedef float f32x4 __attribute__((ext_vector_type(4)));

// ================= one-time converts =================
__global__ void convert_h_kernel(const float* __restrict__ in, f16* __restrict__ out, int n8)
{
  int i = blockIdx.x * 256 + threadIdx.x;
  if (i >= n8) return;
  float4 a = *(const float4*)(in + (size_t)i * 8);
  float4 b = *(const float4*)(in + (size_t)i * 8 + 4);
  f16x8 v;
  v[0] = (f16)a.x; v[1] = (f16)a.y; v[2] = (f16)a.z; v[3] = (f16)a.w;
  v[4] = (f16)b.x; v[5] = (f16)b.y; v[6] = (f16)b.z; v[7] = (f16)b.w;
  *(f16x8*)(out + (size_t)i * 8) = v;
}

// out[m][n][k] = (f16) in_m[k][n], 4 matrices 256x256, blockIdx.y = m
__global__ void transpose_w_kernel(const float* __restrict__ s0, const float* __restrict__ s1,
                                   const float* __restrict__ s2, const float* __restrict__ s3,
                                   f16* __restrict__ out)
{
  int m = blockIdx.y;
  const float* in = (m == 0) ? s0 : (m == 1) ? s1 : (m == 2) ? s2 : s3;
  int t = blockIdx.x * 256 + threadIdx.x;   // 65536
  int n = t >> 8, k = t & 255;
  out[(size_t)m * 65536 + t] = (f16)in[k * 256 + n];
}

// W12T[col][k] (f16, [256][40]): k<8 -> Wp1[k][col], k<16 -> Wp2[k-8][col], else 0
__global__ void w12_kernel(const float* __restrict__ Wp, f16* __restrict__ W12T)
{
  int t = blockIdx.x * 256 + threadIdx.x;   // 10240
  if (t >= 256 * 40) return;
  int col = t / 40, k = t % 40;
  f16 v = (f16)0.f;
  if (k < 8)       v = (f16)Wp[(size_t)(256 + k) * 256 + col];
  else if (k < 16) v = (f16)Wp[(size_t)(264 + (k - 8)) * 256 + col];
  W12T[t] = v;
}

// ================= MFMA GEMM: 128 rows x FULL 256 cols, whole B in LDS =================
// 512 threads = 8 waves (4 row x 2 col); wave = 32 rows x 128 cols.
// MODE 0: feat(f16) = A@B; epilogue el/er (2 heads per wave)
// MODE 1: out(f32) = A@B + t@Wp1 + bo@Wp2 + bp via one extra MFMA; strided store
template<int MODE>
__global__ __launch_bounds__(512)
void gemm_mfma(const f16* __restrict__ A, const f16* __restrict__ BT,
               f16* __restrict__ Ch, float* __restrict__ Cf, int M,
               const float* __restrict__ al, const float* __restrict__ ar,
               float* __restrict__ el, float* __restrict__ er,
               const float* __restrict__ tvec, const float* __restrict__ bvec,
               const f16* __restrict__ W12Tg, const float* __restrict__ bp,
               int ldc, int coff)
{
  __shared__ alignas(16) f16 Bs[256][264];                  // 135 KB
  __shared__ alignas(16) f16 W12s[MODE ? 256 : 1][MODE ? 40 : 8];

  const int tid = threadIdx.x;
  const int lane = tid & 63, wv = tid >> 6;
  const int l15 = lane & 15, lq = lane >> 4;
  const int wr = wv >> 1, wc = wv & 1;
  const int bm = blockIdx.x * 128;
  const int cb = wc * 128;

#pragma unroll
  for (int i = 0; i < 16; ++i) {
    int seg = tid + i * 512;
    int row = seg >> 5;
    int cs = (seg & 31) * 8;
    *(uint4*)&Bs[row][cs] = *(const uint4*)&BT[(size_t)row * 256 + cs];
  }
  if (MODE == 1) {
    for (int i = tid; i < 2560; i += 512)
      ((uint2*)&W12s[0][0])[i] = ((const uint2*)W12Tg)[i];
  }
  __syncthreads();

  const int r0 = bm + wr * 32 + l15;
  const int r1 = r0 + 16;
  const bool ok0 = r0 < M, ok1 = r1 < M;
  const f16* Arow0 = A + (size_t)r0 * 256;
  const f16* Arow1 = A + (size_t)r1 * 256;

  f32x4 acc[2][8] = {};

#pragma unroll
  for (int k0 = 0; k0 < 256; k0 += 32) {
    int ko = k0 + lq * 8;
    f16x8 a0 = {0, 0, 0, 0, 0, 0, 0, 0};
    f16x8 a1 = {0, 0, 0, 0, 0, 0, 0, 0};
    if (ok0) a0 = *(const f16x8*)(Arow0 + ko);
    if (ok1) a1 = *(const f16x8*)(Arow1 + ko);
#pragma unroll
    for (int nf = 0; nf < 8; ++nf) {
      f16x8 bf = *(const f16x8*)&Bs[cb + nf * 16 + l15][ko];
      acc[0][nf] = __builtin_amdgcn_mfma_f32_16x16x32_f16(a0, bf, acc[0][nf], 0, 0, 0);
      acc[1][nf] = __builtin_amdgcn_mfma_f32_16x16x32_f16(a1, bf, acc[1][nf], 0, 0, 0);
    }
  }

  if (MODE == 0) {
    float alv[8], arv[8];
#pragma unroll
    for (int nf = 0; nf < 8; ++nf) {
      alv[nf] = al[cb + nf * 16 + l15];
      arv[nf] = ar[cb + nf * 16 + l15];
    }
#pragma unroll
    for (int m = 0; m < 2; ++m)
#pragma unroll
      for (int i = 0; i < 4; ++i) {
        int row = bm + wr * 32 + m * 16 + lq * 4 + i;
        float peA = 0.f, prA = 0.f, peB = 0.f, prB = 0.f;
#pragma unroll
        for (int nf = 0; nf < 4; ++nf) {
          peA = fmaf(acc[m][nf][i], alv[nf], peA);
          prA = fmaf(acc[m][nf][i], arv[nf], prA);
          peB = fmaf(acc[m][nf + 4][i], alv[nf + 4], peB);
          prB = fmaf(acc[m][nf + 4][i], arv[nf + 4], prB);
        }
#pragma unroll
        for (int o = 8; o >= 1; o >>= 1) {
          peA += __shfl_xor(peA, o, 64);
          prA += __shfl_xor(prA, o, 64);
          peB += __shfl_xor(peB, o, 64);
          prB += __shfl_xor(prB, o, 64);
        }
        if (row < M) {
          if (l15 == 0) {
            int hA = wc * 2;
            el[row * 4 + hA] = peA;     er[row * 4 + hA] = prA;
            el[row * 4 + hA + 1] = peB; er[row * 4 + hA + 1] = prB;
          }
#pragma unroll
          for (int nf = 0; nf < 8; ++nf)
            Ch[(size_t)row * 256 + cb + nf * 16 + l15] = (f16)acc[m][nf][i];
        }
      }
  } else {
    // rank-8 correction via one MFMA per (m, nf): A-frag = [t(8), bo(8), 0(16)]
#pragma unroll
    for (int m = 0; m < 2; ++m) {
      int arow = bm + wr * 32 + m * 16 + l15;
      f16x8 af = {0, 0, 0, 0, 0, 0, 0, 0};
      if (arow < M && lq < 2) {
        const float* srcp = (lq == 0) ? &tvec[(size_t)arow * 8] : &bvec[(size_t)arow * 8];
        float4 x0 = *(const float4*)srcp;
        float4 x1 = *(const float4*)(srcp + 4);
        af[0] = (f16)x0.x; af[1] = (f16)x0.y; af[2] = (f16)x0.z; af[3] = (f16)x0.w;
        af[4] = (f16)x1.x; af[5] = (f16)x1.y; af[6] = (f16)x1.z; af[7] = (f16)x1.w;
      }
#pragma unroll
      for (int nf = 0; nf < 8; ++nf) {
        f16x8 bf2 = *(const f16x8*)&W12s[cb + nf * 16 + l15][lq * 8];
        acc[m][nf] = __builtin_amdgcn_mfma_f32_16x16x32_f16(af, bf2, acc[m][nf], 0, 0, 0);
      }
    }
    float bpv[8];
#pragma unroll
    for (int nf = 0; nf < 8; ++nf) bpv[nf] = bp[cb + nf * 16 + l15];
#pragma unroll
    for (int m = 0; m < 2; ++m)
#pragma unroll
      for (int i = 0; i < 4; ++i) {
        int row = bm + wr * 32 + m * 16 + lq * 4 + i;
        if (row >= M) continue;
#pragma unroll
        for (int nf = 0; nf < 8; ++nf)
          Cf[(size_t)row * ldc + coff + cb + nf * 16 + l15] = acc[m][nf][i] + bpv[nf];
      }
  }
}

// ============== CSR build pass 1: LDS histogram + per-edge local rank ==============
__global__ __launch_bounds__(512)
void hist_kernel(const int* __restrict__ d0, const int* __restrict__ d1,
                 const int* __restrict__ d2, unsigned short* __restrict__ ghist,
                 unsigned short* __restrict__ rank16)
{
  __shared__ unsigned int h32[N_NODES / 2];
  int et = blockIdx.y, b = blockIdx.x, tid = threadIdx.x;
  const int* dst = (et == 0) ? d0 : (et == 1) ? d1 : d2;
  for (int i = tid; i < N_NODES / 2; i += 512) h32[i] = 0u;
  __syncthreads();
  int e0 = b * CHUNK;
  for (int i = tid; i < CHUNK; i += 512) {
    int e = e0 + i;
    int d = dst[e];
    unsigned int sh = (d & 1) * 16;
    unsigned int old = atomicAdd(&h32[d >> 1], 1u << sh);
    rank16[(size_t)et * N_EDGES + e] = (unsigned short)((old >> sh) & 0xFFFFu);
  }
  __syncthreads();
  unsigned short* gh = ghist + ((size_t)(et * NB + b)) * N_NODES;
  for (int d = tid; d < N_NODES; d += 512)
    gh[d] = (unsigned short)((h32[d >> 1] >> ((d & 1) * 16)) & 0xFFFFu);
}

// ============== pass 2: per-dst exclusive prefix over NB blocks + totals ==============
__global__ __launch_bounds__(256)
void blockpfx_kernel(unsigned short* __restrict__ ghist, int* __restrict__ counts)
{
  int d = blockIdx.x * 256 + threadIdx.x;
  int et = blockIdx.y;
  if (d >= N_NODES) return;
  int running = 0;
#pragma unroll
  for (int b = 0; b < NB; ++b) {
    size_t idx = ((size_t)(et * NB + b)) * N_NODES + d;
    int v = ghist[idx];
    ghist[idx] = (unsigned short)running;
    running += v;
  }
  counts[et * N_NODES + d] = running;
}

// ============== batched scan (blockIdx.x = etype) ==============
__global__ __launch_bounds__(1024)
void scan_kernel(int* __restrict__ cc_all, int* __restrict__ off_all, int n, int total)
{
  int et = blockIdx.x;
  int* cc = cc_all + (size_t)et * n;
  int* off = off_all + (size_t)et * (n + 1);
  __shared__ int wsum[16];
  __shared__ int woff[16];
  __shared__ int s_carry, s_chunk;
  int tid = threadIdx.x;
  int lane = tid & 63, wid = tid >> 6;
  if (tid == 0) s_carry = 0;
  __syncthreads();
  for (int base = 0; base < n; base += 1024) {
    int i = base + tid;
    int v = (i < n) ? cc[i] : 0;
    int x = v;
#pragma unroll
    for (int s = 1; s < 64; s <<= 1) {
      int y = __shfl_up(x, s, 64);
      if (lane >= s) x += y;
    }
    if (lane == 63) wsum[wid] = x;
    __syncthreads();
    if (wid == 0 && lane < 16) {
      int ws_ = wsum[lane];
      int xx = ws_;
#pragma unroll
      for (int s = 1; s < 16; s <<= 1) {
        int y = __shfl_up(xx, s, 64);
        if (lane >= s) xx += y;
      }
      woff[lane] = xx - ws_;
      if (lane == 15) s_chunk = xx;
    }
    __syncthreads();
    int excl = s_carry + woff[wid] + (x - v);
    if (i < n) { off[i] = excl; cc[i] = excl; }
    __syncthreads();
    if (tid == 0) s_carry += s_chunk;
    __syncthreads();
  }
  if (tid == 0) off[n] = total;
}

// ============== pass 4: place packed payload src|f16(ew)<<16 (single 4B scatter) ==============
__global__ __launch_bounds__(256)
void place_kernel(const int* __restrict__ d0, const int* __restrict__ d1,
                  const int* __restrict__ d2,
                  const int* __restrict__ s0, const int* __restrict__ s1,
                  const int* __restrict__ s2,
                  const float* __restrict__ w0, const float* __restrict__ w1,
                  const float* __restrict__ w2,
                  const int* __restrict__ off, const unsigned short* __restrict__ ghist,
                  const unsigned short* __restrict__ rank16,
                  unsigned int* __restrict__ csr_pay)
{
  int e = blockIdx.x * 256 + threadIdx.x;
  if (e >= N_EDGES) return;
  int et = blockIdx.y;
  const int* dst = (et == 0) ? d0 : (et == 1) ? d1 : d2;
  const int* src = (et == 0) ? s0 : (et == 1) ? s1 : s2;
  const float* ew = (et == 0) ? w0 : (et == 1) ? w1 : w2;
  int d = dst[e];
  int b = e / CHUNK;
  int pos = off[et * (N_NODES + 1) + d]
          + (int)ghist[((size_t)(et * NB + b)) * N_NODES + d]
          + (int)rank16[(size_t)et * N_EDGES + e];
  unsigned short hw = __half_as_ushort(__float2half_rn(ew[e]));
  csr_pay[(size_t)et * N_EDGES + pos] = (unsigned int)src[e] | ((unsigned int)hw << 16);
}

// ============== column-tiled aggregation: 4 passes of 64 cols (one head each) ==============
// grid (ceil(N/32), 4): blockIdx.y = cp (col pass == head). Wave = 4 nodes x 16 lanes.
// Per pass the feat slice is 64 cols = 3.85 MB -> per-XCD L2 resident.
__global__ __launch_bounds__(512)
void aggregate_kernel(const int* __restrict__ off, const unsigned int* __restrict__ csr_pay,
                      const float* __restrict__ el, const float* __restrict__ er,
                      const __half* __restrict__ feat, const float* __restrict__ bias,
                      __half* __restrict__ gat, int n_nodes)
{
  int tid = threadIdx.x;
  int lane = tid & 63, wv = tid >> 6;     // 8 waves
  int lg = lane >> 4, lc = lane & 15;     // node-sub, col-group
  int cp = blockIdx.y;                    // col pass == head
  int n = blockIdx.x * 32 + wv * 4 + lg;
  if (n >= n_nodes) return;
  int cbase = cp * 64 + lc * 4;

  int e0 = off[n], e1 = off[n + 1];
  float ern = er[(size_t)n * 4 + cp];
  float ac0 = 0.f, ac1 = 0.f, ac2 = 0.f, ac3 = 0.f, dn = 0.f;

  int e = e0;
  for (; e + 3 < e1; e += 4) {
    unsigned int p0 = csr_pay[e], p1 = csr_pay[e + 1];
    unsigned int p2 = csr_pay[e + 2], p3 = csr_pay[e + 3];
    int s0 = (int)(p0 & 0xFFFFu), s1 = (int)(p1 & 0xFFFFu);
    int s2 = (int)(p2 & 0xFFFFu), s3 = (int)(p3 & 0xFFFFu);
    float v0 = el[s0 * 4 + cp] + ern; v0 = v0 > 0.f ? v0 : 0.2f * v0;
    float v1 = el[s1 * 4 + cp] + ern; v1 = v1 > 0.f ? v1 : 0.2f * v1;
    float v2 = el[s2 * 4 + cp] + ern; v2 = v2 > 0.f ? v2 : 0.2f * v2;
    float v3 = el[s3 * 4 + cp] + ern; v3 = v3 > 0.f ? v3 : 0.2f * v3;
    float x0 = __expf(v0), x1 = __expf(v1), x2 = __expf(v2), x3 = __expf(v3);
    dn += x0 + x1 + x2 + x3;
    float c0 = x0 * __half2float(__ushort_as_half((unsigned short)(p0 >> 16)));
    float c1 = x1 * __half2float(__ushort_as_half((unsigned short)(p1 >> 16)));
    float c2 = x2 * __half2float(__ushort_as_half((unsigned short)(p2 >> 16)));
    float c3 = x3 * __half2float(__ushort_as_half((unsigned short)(p3 >> 16)));
    uint2 u0 = *(const uint2*)(feat + (size_t)s0 * 256 + cbase);
    uint2 u1 = *(const uint2*)(feat + (size_t)s1 * 256 + cbase);
    uint2 u2 = *(const uint2*)(feat + (size_t)s2 * 256 + cbase);
    uint2 u3 = *(const uint2*)(feat + (size_t)s3 * 256 + cbase);
    float2 A01 = __half22float2(*(__half2*)&u0.x), A23 = __half22float2(*(__half2*)&u0.y);
    float2 B01 = __half22float2(*(__half2*)&u1.x), B23 = __half22float2(*(__half2*)&u1.y);
    float2 C01 = __half22float2(*(__half2*)&u2.x), C23 = __half22float2(*(__half2*)&u2.y);
    float2 D01 = __half22float2(*(__half2*)&u3.x), D23 = __half22float2(*(__half2*)&u3.y);
    ac0 = fmaf(c0, A01.x, ac0); ac1 = fmaf(c0, A01.y, ac1);
    ac2 = fmaf(c0, A23.x, ac2); ac3 = fmaf(c0, A23.y, ac3);
    ac0 = fmaf(c1, B01.x, ac0); ac1 = fmaf(c1, B01.y, ac1);
    ac2 = fmaf(c1, B23.x, ac2); ac3 = fmaf(c1, B23.y, ac3);
    ac0 = fmaf(c2, C01.x, ac0); ac1 = fmaf(c2, C01.y, ac1);
    ac2 = fmaf(c2, C23.x, ac2); ac3 = fmaf(c2, C23.y, ac3);
    ac0 = fmaf(c3, D01.x, ac0); ac1 = fmaf(c3, D01.y, ac1);
    ac2 = fmaf(c3, D23.x, ac2); ac3 = fmaf(c3, D23.y, ac3);
  }
  for (; e < e1; ++e) {
    unsigned int p0 = csr_pay[e];
    int s0 = (int)(p0 & 0xFFFFu);
    float v0 = el[s0 * 4 + cp] + ern; v0 = v0 > 0.f ? v0 : 0.2f * v0;
    float x0 = __expf(v0);
    dn += x0;
    float c0 = x0 * __half2float(__ushort_as_half((unsigned short)(p0 >> 16)));
    uint2 u0 = *(const uint2*)(feat + (size_t)s0 * 256 + cbase);
    float2 A01 = __half22float2(*(__half2*)&u0.x), A23 = __half22float2(*(__half2*)&u0.y);
    ac0 = fmaf(c0, A01.x, ac0); ac1 = fmaf(c0, A01.y, ac1);
    ac2 = fmaf(c0, A23.x, ac2); ac3 = fmaf(c0, A23.y, ac3);
  }

  float invd = (dn != 0.f) ? 1.f / dn : 0.f;
  float4 bv = *(const float4*)&bias[cbase];
  __half2 h01 = __floats2half2_rn(ac0 * invd + bv.x, ac1 * invd + bv.y);
  __half2 h23 = __floats2half2_rn(ac2 * invd + bv.z, ac3 * invd + bv.w);
  uint2 st;
  st.x = *(unsigned int*)&h01;
  st.y = *(unsigned int*)&h23;
  *(uint2*)&gat[(size_t)n * 256 + cbase] = st;
}

// ============== gt = gat@Wt, gb = gat@Wb  ([N,8] each, f32); wave per node ==============
__global__ __launch_bounds__(256)
void project_tb_kernel(const __half* __restrict__ gat,
                       const float* __restrict__ Wt, const float* __restrict__ Wb,
                       float* __restrict__ gt, float* __restrict__ gb, int n_nodes)
{
  int node = (blockIdx.x * 256 + threadIdx.x) >> 6;
  int lane = threadIdx.x & 63;
  if (node >= n_nodes) return;
  uint2 u = *(const uint2*)(gat + (size_t)node * 256 + lane * 4);
  float2 f01 = __half22float2(*(__half2*)&u.x);
  float2 f23 = __half22float2(*(__half2*)&u.y);
  float f[4] = {f01.x, f01.y, f23.x, f23.y};
  float p[16];
#pragma unroll
  for (int j = 0; j < 16; ++j) p[j] = 0.f;
#pragma unroll
  for (int r = 0; r < 4; ++r) {
    int c = lane * 4 + r;
    const float* wtr = &Wt[(size_t)c * 8];
    const float* wbr = &Wb[(size_t)c * 8];
#pragma unroll
    for (int j = 0; j < 8; ++j) {
      p[j]     = fmaf(f[r], wtr[j], p[j]);
      p[8 + j] = fmaf(f[r], wbr[j], p[8 + j]);
    }
  }
#pragma unroll
  for (int o = 32; o >= 1; o >>= 1) {
#pragma unroll
    for (int j = 0; j < 16; ++j) p[j] += __shfl_xor(p[j], o, 64);
  }
  if (lane == 0) {
    *(float4*)&gt[(size_t)node * 8]     = make_float4(p[0], p[1], p[2], p[3]);
    *(float4*)&gt[(size_t)node * 8 + 4] = make_float4(p[4], p[5], p[6], p[7]);
    *(float4*)&gb[(size_t)node * 8]     = make_float4(p[8], p[9], p[10], p[11]);
    *(float4*)&gb[(size_t)node * 8 + 4] = make_float4(p[12], p[13], p[14], p[15]);
  }
}

// ============== enhance: wave-per-node; rank + tiny gt/gb gathers ==============
__global__ __launch_bounds__(256)
void enhance_pool_kernel(const int* __restrict__ nbr_idx, const float* __restrict__ nbr_w,
                         const float* __restrict__ gt, const float* __restrict__ gb,
                         const float* __restrict__ bt, const float* __restrict__ bb,
                         float* __restrict__ tvec, float* __restrict__ bvec, int n_nodes)
{
  int n = (blockIdx.x * 256 + threadIdx.x) >> 6;
  int lane = threadIdx.x & 63;
  if (n >= n_nodes) return;
  const int l16 = lane & 15;

  float w = nbr_w[(size_t)n * 16 + l16];
  int idx = nbr_idx[(size_t)n * 16 + l16];

  int rhi = 0, rlo = 0;
#pragma unroll
  for (int i = 0; i < 16; ++i) {
    float wi = __shfl(w, i, 64);
    rhi += (wi > w) || (wi == w && i < l16);
    rlo += (wi < w) || (wi == w && i < l16);
  }

  int rows[7];
#pragma unroll
  for (int q = 0; q < 5; ++q) {
    unsigned long long m = __ballot(lane < 16 && rhi == q);
    rows[q] = __shfl(idx, __ffsll(m) - 1, 64);
  }
#pragma unroll
  for (int q = 0; q < 2; ++q) {
    unsigned long long m = __ballot(lane < 16 && rlo == q);
    rows[5 + q] = __shfl(idx, __ffsll(m) - 1, 64);
  }

  int j = lane & 7;
  if (lane < 8) {
    float s = 0.f;
#pragma unroll
    for (int q = 0; q < 5; ++q) s += gt[(size_t)rows[q] * 8 + j];
    tvec[(size_t)n * 8 + j] = s * 0.2f + bt[j];
  } else if (lane < 16) {
    float s = gb[(size_t)rows[5] * 8 + j] + gb[(size_t)rows[6] * 8 + j];
    bvec[(size_t)n * 8 + j] = s * 0.5f + bb[j];
  }
}

extern "C" void kernel_launch(void* const* d_in, const int* in_sizes, int n_in,
                              void* d_out, int out_size, void* d_ws, size_t ws_size,
                              hipStream_t stream)
{
  const int N_ = N_NODES;
  const int E_ = N_EDGES;

  const float* h = (const float*)d_in[0];
  const float* Wt = (const float*)d_in[28];
  const float* bt = (const float*)d_in[29];
  const float* Wb = (const float*)d_in[30];
  const float* bb = (const float*)d_in[31];
  const float* Wp = (const float*)d_in[32];
  const float* bp = (const float*)d_in[33];
  float* out = (float*)d_out;

  char* wsb = (char*)d_ws;
  size_t o = 0;
  auto alloc = [&](size_t bytes) -> void* {
    void* p = wsb + o;
    o = (o + bytes + 255) & ~(size_t)255;
    return p;
  };
  f16*  hf    = (f16*)alloc((size_t)N_ * 256 * 2);
  f16*  feat  = (f16*)alloc((size_t)N_ * 256 * 2);
  f16*  gat   = (f16*)alloc((size_t)N_ * 256 * 2);
  f16*  WT    = (f16*)alloc((size_t)4 * 256 * 256 * 2);   // 3x W + WpT
  f16*  W12T  = (f16*)alloc((size_t)256 * 40 * 2);
  float* el     = (float*)alloc((size_t)N_ * 4 * 4);
  float* er     = (float*)alloc((size_t)N_ * 4 * 4);
  float* gt     = (float*)alloc((size_t)N_ * 8 * 4);
  float* gb     = (float*)alloc((size_t)N_ * 8 * 4);
  float* tvec   = (float*)alloc((size_t)N_ * 8 * 4);
  float* bvec   = (float*)alloc((size_t)N_ * 8 * 4);
  int*   off    = (int*)alloc((size_t)3 * (N_ + 1) * 4);
  int*   counts = (int*)alloc((size_t)3 * N_ * 4);
  unsigned short* ghist = (unsigned short*)alloc((size_t)3 * NB * N_ * 2);  // 11.5 MB
  unsigned short* rank16 = (unsigned short*)alloc((size_t)3 * E_ * 2);
  unsigned int* csr_pay = (unsigned int*)alloc((size_t)3 * E_ * 4);
  (void)ws_size; (void)in_sizes; (void)n_in; (void)out_size;

  const int row_blocks = (N_ + 127) / 128;  // 235
  const int edge_blocks = (E_ + 255) / 256; // 1875
  const int wave_blocks = (N_ + 3) / 4;     // 7500 (enhance/project)
  const int agg_blocks = (N_ + 31) / 32;    // 938 (aggregate, 32 nodes/block)

  const int* d_dst0 = (const int*)d_in[1 + 0 * 9 + 1];
  const int* d_dst1 = (const int*)d_in[1 + 1 * 9 + 1];
  const int* d_dst2 = (const int*)d_in[1 + 2 * 9 + 1];
  const int* d_src0 = (const int*)d_in[1 + 0 * 9 + 0];
  const int* d_src1 = (const int*)d_in[1 + 1 * 9 + 0];
  const int* d_src2 = (const int*)d_in[1 + 2 * 9 + 0];
  const float* d_ew0 = (const float*)d_in[1 + 0 * 9 + 2];
  const float* d_ew1 = (const float*)d_in[1 + 1 * 9 + 2];
  const float* d_ew2 = (const float*)d_in[1 + 2 * 9 + 2];

  // one-time conversions (independent of CSR build)
  convert_h_kernel<<<(N_ * 256 / 8 + 255) / 256, 256, 0, stream>>>(h, hf, N_ * 256 / 8);
  transpose_w_kernel<<<dim3(256, 4), 256, 0, stream>>>(
      (const float*)d_in[1 + 0 * 9 + 5], (const float*)d_in[1 + 1 * 9 + 5],
      (const float*)d_in[1 + 2 * 9 + 5], Wp, WT);
  w12_kernel<<<(256 * 40 + 255) / 256, 256, 0, stream>>>(Wp, W12T);
  f16* WpT = WT + (size_t)3 * 65536;

  // atomic-free CSR build (batched over etypes)
  hist_kernel<<<dim3(NB, 3), 512, 0, stream>>>(d_dst0, d_dst1, d_dst2, ghist, rank16);
  blockpfx_kernel<<<dim3((N_ + 255) / 256, 3), 256, 0, stream>>>(ghist, counts);
  scan_kernel<<<3, 1024, 0, stream>>>(counts, off, N_, E_);
  place_kernel<<<dim3(edge_blocks, 3), 256, 0, stream>>>(
      d_dst0, d_dst1, d_dst2, d_src0, d_src1, d_src2, d_ew0, d_ew1, d_ew2,
      off, ghist, rank16, csr_pay);

  for (int et = 0; et < 3; ++et) {
    const int base = 1 + et * 9;
    const int* nbr_idx = (const int*)d_in[base + 3];
    const float* nbr_w = (const float*)d_in[base + 4];
    const float* al = (const float*)d_in[base + 6];
    const float* ar = (const float*)d_in[base + 7];
    const float* b = (const float*)d_in[base + 8];

    gemm_mfma<0><<<row_blocks, 512, 0, stream>>>(
        hf, WT + (size_t)et * 65536, feat, nullptr, N_, al, ar, el, er,
        nullptr, nullptr, nullptr, nullptr, 256, 0);

    aggregate_kernel<<<dim3(agg_blocks, 4), 512, 0, stream>>>(
        off + (size_t)et * (N_ + 1), csr_pay + (size_t)et * E_,
        el, er, (const __half*)feat, b, (__half*)gat, N_);

    project_tb_kernel<<<wave_blocks, 256, 0, stream>>>(
        (const __half*)gat, Wt, Wb, gt, gb, N_);

    enhance_pool_kernel<<<wave_blocks, 256, 0, stream>>>(
        nbr_idx, nbr_w, gt, gb, bt, bb, tvec, bvec, N_);

    gemm_mfma<1><<<row_blocks, 512, 0, stream>>>(
        gat, WpT, nullptr, out, N_, nullptr, nullptr, nullptr, nullptr,
        tvec, bvec, W12T, bp, 768, et * 256);
  }
}

// Round 16
// 354.648 us; speedup vs baseline: 1.4119x; 1.4119x over previous
//
#include <hip/hip_runtime.h>
#include <hip/hip_fp16.h>

#define N_NODES 30000
#define N_EDGES 480000
#define NB 64           // blocks per etype for counting sort
#define CHUNK 7500      // N_EDGES / NB  (< 65536 so u16 ranks/counts are safe)

typedef _Float16 f16;
typedef f16 f16x8 __attribute__((ext_vector_type(8)));
typedef float f32x4 __attribute__((ext_vector_type(4)));

// ================= one-time converts =================
__global__ void convert_h_kernel(const float* __restrict__ in, f16* __restrict__ out, int n8)
{
  int i = blockIdx.x * 256 + threadIdx.x;
  if (i >= n8) return;
  float4 a = *(const float4*)(in + (size_t)i * 8);
  float4 b = *(const float4*)(in + (size_t)i * 8 + 4);
  f16x8 v;
  v[0] = (f16)a.x; v[1] = (f16)a.y; v[2] = (f16)a.z; v[3] = (f16)a.w;
  v[4] = (f16)b.x; v[5] = (f16)b.y; v[6] = (f16)b.z; v[7] = (f16)b.w;
  *(f16x8*)(out + (size_t)i * 8) = v;
}

// out[m][n][k] = (f16) in_m[k][n], 4 matrices 256x256, blockIdx.y = m
__global__ void transpose_w_kernel(const float* __restrict__ s0, const float* __restrict__ s1,
                                   const float* __restrict__ s2, const float* __restrict__ s3,
                                   f16* __restrict__ out)
{
  int m = blockIdx.y;
  const float* in = (m == 0) ? s0 : (m == 1) ? s1 : (m == 2) ? s2 : s3;
  int t = blockIdx.x * 256 + threadIdx.x;   // 65536
  int n = t >> 8, k = t & 255;
  out[(size_t)m * 65536 + t] = (f16)in[k * 256 + n];
}

// W12T[col][k] (f16, [256][40]): k<8 -> Wp1[k][col], k<16 -> Wp2[k-8][col], else 0
__global__ void w12_kernel(const float* __restrict__ Wp, f16* __restrict__ W12T)
{
  int t = blockIdx.x * 256 + threadIdx.x;   // 10240
  if (t >= 256 * 40) return;
  int col = t / 40, k = t % 40;
  f16 v = (f16)0.f;
  if (k < 8)       v = (f16)Wp[(size_t)(256 + k) * 256 + col];
  else if (k < 16) v = (f16)Wp[(size_t)(264 + (k - 8)) * 256 + col];
  W12T[t] = v;
}

// W16T[j][k] (f16, [16][256]): j<8 -> Wt[k][j], else Wb[k][j-8]
__global__ void w16_kernel(const float* __restrict__ Wt, const float* __restrict__ Wb,
                           f16* __restrict__ W16T)
{
  int t = blockIdx.x * 256 + threadIdx.x;   // 4096
  if (t >= 16 * 256) return;
  int j = t >> 8, k = t & 255;
  W16T[t] = (f16)((j < 8) ? Wt[(size_t)k * 8 + j] : Wb[(size_t)k * 8 + (j - 8)]);
}

// ================= MFMA GEMM: 128 rows x FULL 256 cols, whole B in LDS =================
// 512 threads = 8 waves (4 row x 2 col); wave = 32 rows x 128 cols.
// MODE 0: feat(f16) = A@B; epilogue el/er (2 heads per wave)
// MODE 1: out(f32) = A@B + t@Wp1 + bo@Wp2 + bp via one extra MFMA; strided store
template<int MODE>
__global__ __launch_bounds__(512)
void gemm_mfma(const f16* __restrict__ A, const f16* __restrict__ BT,
               f16* __restrict__ Ch, float* __restrict__ Cf, int M,
               const float* __restrict__ al, const float* __restrict__ ar,
               float* __restrict__ el, float* __restrict__ er,
               const float* __restrict__ tvec, const float* __restrict__ bvec,
               const f16* __restrict__ W12Tg, const float* __restrict__ bp,
               int ldc, int coff)
{
  __shared__ alignas(16) f16 Bs[256][264];                  // 135 KB
  __shared__ alignas(16) f16 W12s[MODE ? 256 : 1][MODE ? 40 : 8];

  const int tid = threadIdx.x;
  const int lane = tid & 63, wv = tid >> 6;
  const int l15 = lane & 15, lq = lane >> 4;
  const int wr = wv >> 1, wc = wv & 1;
  const int bm = blockIdx.x * 128;
  const int cb = wc * 128;

#pragma unroll
  for (int i = 0; i < 16; ++i) {
    int seg = tid + i * 512;
    int row = seg >> 5;
    int cs = (seg & 31) * 8;
    *(uint4*)&Bs[row][cs] = *(const uint4*)&BT[(size_t)row * 256 + cs];
  }
  if (MODE == 1) {
    for (int i = tid; i < 2560; i += 512)
      ((uint2*)&W12s[0][0])[i] = ((const uint2*)W12Tg)[i];
  }
  __syncthreads();

  const int r0 = bm + wr * 32 + l15;
  const int r1 = r0 + 16;
  const bool ok0 = r0 < M, ok1 = r1 < M;
  const f16* Arow0 = A + (size_t)r0 * 256;
  const f16* Arow1 = A + (size_t)r1 * 256;

  f32x4 acc[2][8] = {};

#pragma unroll
  for (int k0 = 0; k0 < 256; k0 += 32) {
    int ko = k0 + lq * 8;
    f16x8 a0 = {0, 0, 0, 0, 0, 0, 0, 0};
    f16x8 a1 = {0, 0, 0, 0, 0, 0, 0, 0};
    if (ok0) a0 = *(const f16x8*)(Arow0 + ko);
    if (ok1) a1 = *(const f16x8*)(Arow1 + ko);
#pragma unroll
    for (int nf = 0; nf < 8; ++nf) {
      f16x8 bf = *(const f16x8*)&Bs[cb + nf * 16 + l15][ko];
      acc[0][nf] = __builtin_amdgcn_mfma_f32_16x16x32_f16(a0, bf, acc[0][nf], 0, 0, 0);
      acc[1][nf] = __builtin_amdgcn_mfma_f32_16x16x32_f16(a1, bf, acc[1][nf], 0, 0, 0);
    }
  }

  if (MODE == 0) {
    float alv[8], arv[8];
#pragma unroll
    for (int nf = 0; nf < 8; ++nf) {
      alv[nf] = al[cb + nf * 16 + l15];
      arv[nf] = ar[cb + nf * 16 + l15];
    }
#pragma unroll
    for (int m = 0; m < 2; ++m)
#pragma unroll
      for (int i = 0; i < 4; ++i) {
        int row = bm + wr * 32 + m * 16 + lq * 4 + i;
        float peA = 0.f, prA = 0.f, peB = 0.f, prB = 0.f;
#pragma unroll
        for (int nf = 0; nf < 4; ++nf) {
          peA = fmaf(acc[m][nf][i], alv[nf], peA);
          prA = fmaf(acc[m][nf][i], arv[nf], prA);
          peB = fmaf(acc[m][nf + 4][i], alv[nf + 4], peB);
          prB = fmaf(acc[m][nf + 4][i], arv[nf + 4], prB);
        }
#pragma unroll
        for (int o = 8; o >= 1; o >>= 1) {
          peA += __shfl_xor(peA, o, 64);
          prA += __shfl_xor(prA, o, 64);
          peB += __shfl_xor(peB, o, 64);
          prB += __shfl_xor(prB, o, 64);
        }
        if (row < M) {
          if (l15 == 0) {
            int hA = wc * 2;
            el[row * 4 + hA] = peA;     er[row * 4 + hA] = prA;
            el[row * 4 + hA + 1] = peB; er[row * 4 + hA + 1] = prB;
          }
#pragma unroll
          for (int nf = 0; nf < 8; ++nf)
            Ch[(size_t)row * 256 + cb + nf * 16 + l15] = (f16)acc[m][nf][i];
        }
      }
  } else {
    // rank-8 correction via one MFMA per (m, nf): A-frag = [t(8), bo(8), 0(16)]
#pragma unroll
    for (int m = 0; m < 2; ++m) {
      int arow = bm + wr * 32 + m * 16 + l15;
      f16x8 af = {0, 0, 0, 0, 0, 0, 0, 0};
      if (arow < M && lq < 2) {
        const float* srcp = (lq == 0) ? &tvec[(size_t)arow * 8] : &bvec[(size_t)arow * 8];
        float4 x0 = *(const float4*)srcp;
        float4 x1 = *(const float4*)(srcp + 4);
        af[0] = (f16)x0.x; af[1] = (f16)x0.y; af[2] = (f16)x0.z; af[3] = (f16)x0.w;
        af[4] = (f16)x1.x; af[5] = (f16)x1.y; af[6] = (f16)x1.z; af[7] = (f16)x1.w;
      }
#pragma unroll
      for (int nf = 0; nf < 8; ++nf) {
        f16x8 bf2 = *(const f16x8*)&W12s[cb + nf * 16 + l15][lq * 8];
        acc[m][nf] = __builtin_amdgcn_mfma_f32_16x16x32_f16(af, bf2, acc[m][nf], 0, 0, 0);
      }
    }
    float bpv[8];
#pragma unroll
    for (int nf = 0; nf < 8; ++nf) bpv[nf] = bp[cb + nf * 16 + l15];
#pragma unroll
    for (int m = 0; m < 2; ++m)
#pragma unroll
      for (int i = 0; i < 4; ++i) {
        int row = bm + wr * 32 + m * 16 + lq * 4 + i;
        if (row >= M) continue;
#pragma unroll
        for (int nf = 0; nf < 8; ++nf)
          Cf[(size_t)row * ldc + coff + cb + nf * 16 + l15] = acc[m][nf][i] + bpv[nf];
      }
  }
}

// ============== CSR build pass 1: LDS histogram + per-edge local rank ==============
__global__ __launch_bounds__(512)
void hist_kernel(const int* __restrict__ d0, const int* __restrict__ d1,
                 const int* __restrict__ d2, unsigned short* __restrict__ ghist,
                 unsigned short* __restrict__ rank16)
{
  __shared__ unsigned int h32[N_NODES / 2];
  int et = blockIdx.y, b = blockIdx.x, tid = threadIdx.x;
  const int* dst = (et == 0) ? d0 : (et == 1) ? d1 : d2;
  for (int i = tid; i < N_NODES / 2; i += 512) h32[i] = 0u;
  __syncthreads();
  int e0 = b * CHUNK;
  for (int i = tid; i < CHUNK; i += 512) {
    int e = e0 + i;
    int d = dst[e];
    unsigned int sh = (d & 1) * 16;
    unsigned int old = atomicAdd(&h32[d >> 1], 1u << sh);
    rank16[(size_t)et * N_EDGES + e] = (unsigned short)((old >> sh) & 0xFFFFu);
  }
  __syncthreads();
  unsigned short* gh = ghist + ((size_t)(et * NB + b)) * N_NODES;
  for (int d = tid; d < N_NODES; d += 512)
    gh[d] = (unsigned short)((h32[d >> 1] >> ((d & 1) * 16)) & 0xFFFFu);
}

// ============== pass 2: per-dst exclusive prefix over NB blocks + totals ==============
__global__ __launch_bounds__(256)
void blockpfx_kernel(unsigned short* __restrict__ ghist, int* __restrict__ counts)
{
  int d = blockIdx.x * 256 + threadIdx.x;
  int et = blockIdx.y;
  if (d >= N_NODES) return;
  int running = 0;
#pragma unroll
  for (int b = 0; b < NB; ++b) {
    size_t idx = ((size_t)(et * NB + b)) * N_NODES + d;
    int v = ghist[idx];
    ghist[idx] = (unsigned short)running;
    running += v;
  }
  counts[et * N_NODES + d] = running;
}

// ============== batched scan (blockIdx.x = etype) ==============
__global__ __launch_bounds__(1024)
void scan_kernel(int* __restrict__ cc_all, int* __restrict__ off_all, int n, int total)
{
  int et = blockIdx.x;
  int* cc = cc_all + (size_t)et * n;
  int* off = off_all + (size_t)et * (n + 1);
  __shared__ int wsum[16];
  __shared__ int woff[16];
  __shared__ int s_carry, s_chunk;
  int tid = threadIdx.x;
  int lane = tid & 63, wid = tid >> 6;
  if (tid == 0) s_carry = 0;
  __syncthreads();
  for (int base = 0; base < n; base += 1024) {
    int i = base + tid;
    int v = (i < n) ? cc[i] : 0;
    int x = v;
#pragma unroll
    for (int s = 1; s < 64; s <<= 1) {
      int y = __shfl_up(x, s, 64);
      if (lane >= s) x += y;
    }
    if (lane == 63) wsum[wid] = x;
    __syncthreads();
    if (wid == 0 && lane < 16) {
      int ws_ = wsum[lane];
      int xx = ws_;
#pragma unroll
      for (int s = 1; s < 16; s <<= 1) {
        int y = __shfl_up(xx, s, 64);
        if (lane >= s) xx += y;
      }
      woff[lane] = xx - ws_;
      if (lane == 15) s_chunk = xx;
    }
    __syncthreads();
    int excl = s_carry + woff[wid] + (x - v);
    if (i < n) { off[i] = excl; cc[i] = excl; }
    __syncthreads();
    if (tid == 0) s_carry += s_chunk;
    __syncthreads();
  }
  if (tid == 0) off[n] = total;
}

// ============== pass 4: place packed payload src|f16(ew)<<16 (single 4B scatter) ==============
__global__ __launch_bounds__(256)
void place_kernel(const int* __restrict__ d0, const int* __restrict__ d1,
                  const int* __restrict__ d2,
                  const int* __restrict__ s0, const int* __restrict__ s1,
                  const int* __restrict__ s2,
                  const float* __restrict__ w0, const float* __restrict__ w1,
                  const float* __restrict__ w2,
                  const int* __restrict__ off, const unsigned short* __restrict__ ghist,
                  const unsigned short* __restrict__ rank16,
                  unsigned int* __restrict__ csr_pay)
{
  int e = blockIdx.x * 256 + threadIdx.x;
  if (e >= N_EDGES) return;
  int et = blockIdx.y;
  const int* dst = (et == 0) ? d0 : (et == 1) ? d1 : d2;
  const int* src = (et == 0) ? s0 : (et == 1) ? s1 : s2;
  const float* ew = (et == 0) ? w0 : (et == 1) ? w1 : w2;
  int d = dst[e];
  int b = e / CHUNK;
  int pos = off[et * (N_NODES + 1) + d]
          + (int)ghist[((size_t)(et * NB + b)) * N_NODES + d]
          + (int)rank16[(size_t)et * N_EDGES + e];
  unsigned short hw = __half_as_ushort(__float2half_rn(ew[e]));
  csr_pay[(size_t)et * N_EDGES + pos] = (unsigned int)src[e] | ((unsigned int)hw << 16);
}

// ============== column-tiled aggregation: 4 passes of 64 cols (one head each) ==============
__global__ __launch_bounds__(512)
void aggregate_kernel(const int* __restrict__ off, const unsigned int* __restrict__ csr_pay,
                      const float* __restrict__ el, const float* __restrict__ er,
                      const __half* __restrict__ feat, const float* __restrict__ bias,
                      __half* __restrict__ gat, int n_nodes)
{
  int tid = threadIdx.x;
  int lane = tid & 63, wv = tid >> 6;     // 8 waves
  int lg = lane >> 4, lc = lane & 15;     // node-sub, col-group
  int cp = blockIdx.y;                    // col pass == head
  int n = blockIdx.x * 32 + wv * 4 + lg;
  if (n >= n_nodes) return;
  int cbase = cp * 64 + lc * 4;

  int e0 = off[n], e1 = off[n + 1];
  float ern = er[(size_t)n * 4 + cp];
  float ac0 = 0.f, ac1 = 0.f, ac2 = 0.f, ac3 = 0.f, dn = 0.f;

  int e = e0;
  for (; e + 3 < e1; e += 4) {
    unsigned int p0 = csr_pay[e], p1 = csr_pay[e + 1];
    unsigned int p2 = csr_pay[e + 2], p3 = csr_pay[e + 3];
    int s0 = (int)(p0 & 0xFFFFu), s1 = (int)(p1 & 0xFFFFu);
    int s2 = (int)(p2 & 0xFFFFu), s3 = (int)(p3 & 0xFFFFu);
    float v0 = el[s0 * 4 + cp] + ern; v0 = v0 > 0.f ? v0 : 0.2f * v0;
    float v1 = el[s1 * 4 + cp] + ern; v1 = v1 > 0.f ? v1 : 0.2f * v1;
    float v2 = el[s2 * 4 + cp] + ern; v2 = v2 > 0.f ? v2 : 0.2f * v2;
    float v3 = el[s3 * 4 + cp] + ern; v3 = v3 > 0.f ? v3 : 0.2f * v3;
    float x0 = __expf(v0), x1 = __expf(v1), x2 = __expf(v2), x3 = __expf(v3);
    dn += x0 + x1 + x2 + x3;
    float c0 = x0 * __half2float(__ushort_as_half((unsigned short)(p0 >> 16)));
    float c1 = x1 * __half2float(__ushort_as_half((unsigned short)(p1 >> 16)));
    float c2 = x2 * __half2float(__ushort_as_half((unsigned short)(p2 >> 16)));
    float c3 = x3 * __half2float(__ushort_as_half((unsigned short)(p3 >> 16)));
    uint2 u0 = *(const uint2*)(feat + (size_t)s0 * 256 + cbase);
    uint2 u1 = *(const uint2*)(feat + (size_t)s1 * 256 + cbase);
    uint2 u2 = *(const uint2*)(feat + (size_t)s2 * 256 + cbase);
    uint2 u3 = *(const uint2*)(feat + (size_t)s3 * 256 + cbase);
    float2 A01 = __half22float2(*(__half2*)&u0.x), A23 = __half22float2(*(__half2*)&u0.y);
    float2 B01 = __half22float2(*(__half2*)&u1.x), B23 = __half22float2(*(__half2*)&u1.y);
    float2 C01 = __half22float2(*(__half2*)&u2.x), C23 = __half22float2(*(__half2*)&u2.y);
    float2 D01 = __half22float2(*(__half2*)&u3.x), D23 = __half22float2(*(__half2*)&u3.y);
    ac0 = fmaf(c0, A01.x, ac0); ac1 = fmaf(c0, A01.y, ac1);
    ac2 = fmaf(c0, A23.x, ac2); ac3 = fmaf(c0, A23.y, ac3);
    ac0 = fmaf(c1, B01.x, ac0); ac1 = fmaf(c1, B01.y, ac1);
    ac2 = fmaf(c1, B23.x, ac2); ac3 = fmaf(c1, B23.y, ac3);
    ac0 = fmaf(c2, C01.x, ac0); ac1 = fmaf(c2, C01.y, ac1);
    ac2 = fmaf(c2, C23.x, ac2); ac3 = fmaf(c2, C23.y, ac3);
    ac0 = fmaf(c3, D01.x, ac0); ac1 = fmaf(c3, D01.y, ac1);
    ac2 = fmaf(c3, D23.x, ac2); ac3 = fmaf(c3, D23.y, ac3);
  }
  for (; e < e1; ++e) {
    unsigned int p0 = csr_pay[e];
    int s0 = (int)(p0 & 0xFFFFu);
    float v0 = el[s0 * 4 + cp] + ern; v0 = v0 > 0.f ? v0 : 0.2f * v0;
    float x0 = __expf(v0);
    dn += x0;
    float c0 = x0 * __half2float(__ushort_as_half((unsigned short)(p0 >> 16)));
    uint2 u0 = *(const uint2*)(feat + (size_t)s0 * 256 + cbase);
    float2 A01 = __half22float2(*(__half2*)&u0.x), A23 = __half22float2(*(__half2*)&u0.y);
    ac0 = fmaf(c0, A01.x, ac0); ac1 = fmaf(c0, A01.y, ac1);
    ac2 = fmaf(c0, A23.x, ac2); ac3 = fmaf(c0, A23.y, ac3);
  }

  float invd = (dn != 0.f) ? 1.f / dn : 0.f;
  float4 bv = *(const float4*)&bias[cbase];
  __half2 h01 = __floats2half2_rn(ac0 * invd + bv.x, ac1 * invd + bv.y);
  __half2 h23 = __floats2half2_rn(ac2 * invd + bv.z, ac3 * invd + bv.w);
  uint2 st;
  st.x = *(unsigned int*)&h01;
  st.y = *(unsigned int*)&h23;
  *(uint2*)&gat[(size_t)n * 256 + cbase] = st;
}

// ============== [gt|gb] = gat @ W16 via MFMA: 256 threads, 4 waves x 32 rows ==============
__global__ __launch_bounds__(256)
void project_mfma_kernel(const f16* __restrict__ gat, const f16* __restrict__ W16T,
                         float* __restrict__ gt, float* __restrict__ gb, int M)
{
  __shared__ alignas(16) f16 Ws[16][256];   // 8 KB
  int tid = threadIdx.x;
  for (int i = tid; i < 512; i += 256)
    ((uint4*)&Ws[0][0])[i] = ((const uint4*)W16T)[i];
  __syncthreads();

  int lane = tid & 63, wv = tid >> 6;
  int l15 = lane & 15, lq = lane >> 4;
  int bm = blockIdx.x * 128 + wv * 32;
  int r0 = bm + l15, r1 = r0 + 16;
  bool ok0 = r0 < M, ok1 = r1 < M;

  f32x4 acc[2] = {};
#pragma unroll
  for (int k0 = 0; k0 < 256; k0 += 32) {
    int ko = k0 + lq * 8;
    f16x8 a0 = {0, 0, 0, 0, 0, 0, 0, 0};
    f16x8 a1 = {0, 0, 0, 0, 0, 0, 0, 0};
    if (ok0) a0 = *(const f16x8*)(gat + (size_t)r0 * 256 + ko);
    if (ok1) a1 = *(const f16x8*)(gat + (size_t)r1 * 256 + ko);
    f16x8 bf = *(const f16x8*)&Ws[l15][ko];
    acc[0] = __builtin_amdgcn_mfma_f32_16x16x32_f16(a0, bf, acc[0], 0, 0, 0);
    acc[1] = __builtin_amdgcn_mfma_f32_16x16x32_f16(a1, bf, acc[1], 0, 0, 0);
  }
#pragma unroll
  for (int m = 0; m < 2; ++m)
#pragma unroll
    for (int i = 0; i < 4; ++i) {
      int row = bm + m * 16 + lq * 4 + i;
      if (row >= M) continue;
      float v = acc[m][i];
      if (l15 < 8) gt[(size_t)row * 8 + l15] = v;
      else         gb[(size_t)row * 8 + (l15 - 8)] = v;
    }
}

// ============== enhance: wave-per-node; rank + tiny gt/gb gathers ==============
__global__ __launch_bounds__(256)
void enhance_pool_kernel(const int* __restrict__ nbr_idx, const float* __restrict__ nbr_w,
                         const float* __restrict__ gt, const float* __restrict__ gb,
                         const float* __restrict__ bt, const float* __restrict__ bb,
                         float* __restrict__ tvec, float* __restrict__ bvec, int n_nodes)
{
  int n = (blockIdx.x * 256 + threadIdx.x) >> 6;
  int lane = threadIdx.x & 63;
  if (n >= n_nodes) return;
  const int l16 = lane & 15;

  float w = nbr_w[(size_t)n * 16 + l16];
  int idx = nbr_idx[(size_t)n * 16 + l16];

  int rhi = 0, rlo = 0;
#pragma unroll
  for (int i = 0; i < 16; ++i) {
    float wi = __shfl(w, i, 64);
    rhi += (wi > w) || (wi == w && i < l16);
    rlo += (wi < w) || (wi == w && i < l16);
  }

  int rows[7];
#pragma unroll
  for (int q = 0; q < 5; ++q) {
    unsigned long long m = __ballot(lane < 16 && rhi == q);
    rows[q] = __shfl(idx, __ffsll(m) - 1, 64);
  }
#pragma unroll
  for (int q = 0; q < 2; ++q) {
    unsigned long long m = __ballot(lane < 16 && rlo == q);
    rows[5 + q] = __shfl(idx, __ffsll(m) - 1, 64);
  }

  int j = lane & 7;
  if (lane < 8) {
    float s = 0.f;
#pragma unroll
    for (int q = 0; q < 5; ++q) s += gt[(size_t)rows[q] * 8 + j];
    tvec[(size_t)n * 8 + j] = s * 0.2f + bt[j];
  } else if (lane < 16) {
    float s = gb[(size_t)rows[5] * 8 + j] + gb[(size_t)rows[6] * 8 + j];
    bvec[(size_t)n * 8 + j] = s * 0.5f + bb[j];
  }
}

extern "C" void kernel_launch(void* const* d_in, const int* in_sizes, int n_in,
                              void* d_out, int out_size, void* d_ws, size_t ws_size,
                              hipStream_t stream)
{
  const int N_ = N_NODES;
  const int E_ = N_EDGES;

  const float* h = (const float*)d_in[0];
  const float* Wt = (const float*)d_in[28];
  const float* bt = (const float*)d_in[29];
  const float* Wb = (const float*)d_in[30];
  const float* bb = (const float*)d_in[31];
  const float* Wp = (const float*)d_in[32];
  const float* bp = (const float*)d_in[33];
  float* out = (float*)d_out;

  char* wsb = (char*)d_ws;
  size_t o = 0;
  auto alloc = [&](size_t bytes) -> void* {
    void* p = wsb + o;
    o = (o + bytes + 255) & ~(size_t)255;
    return p;
  };
  f16*  hf    = (f16*)alloc((size_t)N_ * 256 * 2);
  f16*  feat  = (f16*)alloc((size_t)N_ * 256 * 2);
  f16*  gat   = (f16*)alloc((size_t)N_ * 256 * 2);
  f16*  WT    = (f16*)alloc((size_t)4 * 256 * 256 * 2);   // 3x W + WpT
  f16*  W12T  = (f16*)alloc((size_t)256 * 40 * 2);
  f16*  W16T  = (f16*)alloc((size_t)16 * 256 * 2);
  float* el     = (float*)alloc((size_t)N_ * 4 * 4);
  float* er     = (float*)alloc((size_t)N_ * 4 * 4);
  float* gt     = (float*)alloc((size_t)N_ * 8 * 4);
  float* gb     = (float*)alloc((size_t)N_ * 8 * 4);
  float* tvec   = (float*)alloc((size_t)N_ * 8 * 4);
  float* bvec   = (float*)alloc((size_t)N_ * 8 * 4);
  int*   off    = (int*)alloc((size_t)3 * (N_ + 1) * 4);
  int*   counts = (int*)alloc((size_t)3 * N_ * 4);
  unsigned short* ghist = (unsigned short*)alloc((size_t)3 * NB * N_ * 2);  // 11.5 MB
  unsigned short* rank16 = (unsigned short*)alloc((size_t)3 * E_ * 2);
  unsigned int* csr_pay = (unsigned int*)alloc((size_t)3 * E_ * 4);
  (void)ws_size; (void)in_sizes; (void)n_in; (void)out_size;

  const int row_blocks = (N_ + 127) / 128;  // 235
  const int edge_blocks = (E_ + 255) / 256; // 1875
  const int wave_blocks = (N_ + 3) / 4;     // 7500 (enhance)
  const int agg_blocks = (N_ + 31) / 32;    // 938 (aggregate, 32 nodes/block)

  const int* d_dst0 = (const int*)d_in[1 + 0 * 9 + 1];
  const int* d_dst1 = (const int*)d_in[1 + 1 * 9 + 1];
  const int* d_dst2 = (const int*)d_in[1 + 2 * 9 + 1];
  const int* d_src0 = (const int*)d_in[1 + 0 * 9 + 0];
  const int* d_src1 = (const int*)d_in[1 + 1 * 9 + 0];
  const int* d_src2 = (const int*)d_in[1 + 2 * 9 + 0];
  const float* d_ew0 = (const float*)d_in[1 + 0 * 9 + 2];
  const float* d_ew1 = (const float*)d_in[1 + 1 * 9 + 2];
  const float* d_ew2 = (const float*)d_in[1 + 2 * 9 + 2];

  // one-time conversions (independent of CSR build)
  convert_h_kernel<<<(N_ * 256 / 8 + 255) / 256, 256, 0, stream>>>(h, hf, N_ * 256 / 8);
  transpose_w_kernel<<<dim3(256, 4), 256, 0, stream>>>(
      (const float*)d_in[1 + 0 * 9 + 5], (const float*)d_in[1 + 1 * 9 + 5],
      (const float*)d_in[1 + 2 * 9 + 5], Wp, WT);
  w12_kernel<<<(256 * 40 + 255) / 256, 256, 0, stream>>>(Wp, W12T);
  w16_kernel<<<16, 256, 0, stream>>>(Wt, Wb, W16T);
  f16* WpT = WT + (size_t)3 * 65536;

  // atomic-free CSR build (batched over etypes)
  hist_kernel<<<dim3(NB, 3), 512, 0, stream>>>(d_dst0, d_dst1, d_dst2, ghist, rank16);
  blockpfx_kernel<<<dim3((N_ + 255) / 256, 3), 256, 0, stream>>>(ghist, counts);
  scan_kernel<<<3, 1024, 0, stream>>>(counts, off, N_, E_);
  place_kernel<<<dim3(edge_blocks, 3), 256, 0, stream>>>(
      d_dst0, d_dst1, d_dst2, d_src0, d_src1, d_src2, d_ew0, d_ew1, d_ew2,
      off, ghist, rank16, csr_pay);

  for (int et = 0; et < 3; ++et) {
    const int base = 1 + et * 9;
    const int* nbr_idx = (const int*)d_in[base + 3];
    const float* nbr_w = (const float*)d_in[base + 4];
    const float* al = (const float*)d_in[base + 6];
    const float* ar = (const float*)d_in[base + 7];
    const float* b = (const float*)d_in[base + 8];

    gemm_mfma<0><<<row_blocks, 512, 0, stream>>>(
        hf, WT + (size_t)et * 65536, feat, nullptr, N_, al, ar, el, er,
        nullptr, nullptr, nullptr, nullptr, 256, 0);

    aggregate_kernel<<<dim3(agg_blocks, 4), 512, 0, stream>>>(
        off + (size_t)et * (N_ + 1), csr_pay + (size_t)et * E_,
        el, er, (const __half*)feat, b, (__half*)gat, N_);

    project_mfma_kernel<<<row_blocks, 256, 0, stream>>>(
        gat, W16T, gt, gb, N_);

    enhance_pool_kernel<<<wave_blocks, 256, 0, stream>>>(
        nbr_idx, nbr_w, gt, gb, bt, bb, tvec, bvec, N_);

    gemm_mfma<1><<<row_blocks, 512, 0, stream>>>(
        gat, WpT, nullptr, out, N_, nullptr, nullptr, nullptr, nullptr,
        tvec, bvec, W12T, bp, 768, et * 256);
  }
}

// Round 17
// 338.752 us; speedup vs baseline: 1.4781x; 1.0469x over previous
//
#include <hip/hip_runtime.h>
#include <hip/hip_fp16.h>

#define N_NODES 30000
#define N_EDGES 480000
#define NB 64           // blocks per etype for counting sort
#define CHUNK 7500      // N_EDGES / NB  (< 65536 so u16 ranks/counts are safe)

typedef _Float16 f16;
typedef f16 f16x8 __attribute__((ext_vector_type(8)));
typedef float f32x4 __attribute__((ext_vector_type(4)));

// ================= one-time converts =================
__global__ void convert_h_kernel(const float* __restrict__ in, f16* __restrict__ out, int n8)
{
  int i = blockIdx.x * 256 + threadIdx.x;
  if (i >= n8) return;
  float4 a = *(const float4*)(in + (size_t)i * 8);
  float4 b = *(const float4*)(in + (size_t)i * 8 + 4);
  f16x8 v;
  v[0] = (f16)a.x; v[1] = (f16)a.y; v[2] = (f16)a.z; v[3] = (f16)a.w;
  v[4] = (f16)b.x; v[5] = (f16)b.y; v[6] = (f16)b.z; v[7] = (f16)b.w;
  *(f16x8*)(out + (size_t)i * 8) = v;
}

// out[m][n][k] = (f16) in_m[k][n], 4 matrices 256x256, blockIdx.y = m
__global__ void transpose_w_kernel(const float* __restrict__ s0, const float* __restrict__ s1,
                                   const float* __restrict__ s2, const float* __restrict__ s3,
                                   f16* __restrict__ out)
{
  int m = blockIdx.y;
  const float* in = (m == 0) ? s0 : (m == 1) ? s1 : (m == 2) ? s2 : s3;
  int t = blockIdx.x * 256 + threadIdx.x;   // 65536
  int n = t >> 8, k = t & 255;
  out[(size_t)m * 65536 + t] = (f16)in[k * 256 + n];
}

// W12T[col][k] (f16, [256][40]): k<8 -> Wp1[k][col], k<16 -> Wp2[k-8][col], else 0
__global__ void w12_kernel(const float* __restrict__ Wp, f16* __restrict__ W12T)
{
  int t = blockIdx.x * 256 + threadIdx.x;   // 10240
  if (t >= 256 * 40) return;
  int col = t / 40, k = t % 40;
  f16 v = (f16)0.f;
  if (k < 8)       v = (f16)Wp[(size_t)(256 + k) * 256 + col];
  else if (k < 16) v = (f16)Wp[(size_t)(264 + (k - 8)) * 256 + col];
  W12T[t] = v;
}

// W16T[j][k] (f16, [16][256]): j<8 -> Wt[k][j], else Wb[k][j-8]
__global__ void w16_kernel(const float* __restrict__ Wt, const float* __restrict__ Wb,
                           f16* __restrict__ W16T)
{
  int t = blockIdx.x * 256 + threadIdx.x;   // 4096
  if (t >= 16 * 256) return;
  int j = t >> 8, k = t & 255;
  W16T[t] = (f16)((j < 8) ? Wt[(size_t)k * 8 + j] : Wb[(size_t)k * 8 + (j - 8)]);
}

// pack al/ar/b for 3 etypes into contiguous [3][256] buffers
__global__ void pack_params_kernel(const float* __restrict__ al0, const float* __restrict__ al1,
                                   const float* __restrict__ al2,
                                   const float* __restrict__ ar0, const float* __restrict__ ar1,
                                   const float* __restrict__ ar2,
                                   const float* __restrict__ b0, const float* __restrict__ b1,
                                   const float* __restrict__ b2,
                                   float* __restrict__ al_all, float* __restrict__ ar_all,
                                   float* __restrict__ b_all)
{
  int et = blockIdx.x, t = threadIdx.x;
  const float* al = (et == 0) ? al0 : (et == 1) ? al1 : al2;
  const float* ar = (et == 0) ? ar0 : (et == 1) ? ar1 : ar2;
  const float* b  = (et == 0) ? b0 : (et == 1) ? b1 : b2;
  al_all[et * 256 + t] = al[t];
  ar_all[et * 256 + t] = ar[t];
  b_all[et * 256 + t]  = b[t];
}

// ================= MFMA GEMM: 128 rows x FULL 256 cols, whole B in LDS, batched over et =================
// grid (row_blocks, 3). 512 threads = 8 waves (4 row x 2 col).
// MODE 0: feat[et](f16) = hf@B[et]; epilogue el/er[et]
// MODE 1: out(f32, coff=et*256) = gat[et]@WpT + t@Wp1 + bo@Wp2 + bp via one extra MFMA
template<int MODE>
__global__ __launch_bounds__(512)
void gemm_mfma(const f16* __restrict__ Abase, const f16* __restrict__ BTbase,
               f16* __restrict__ Chbase, float* __restrict__ Cf, int M,
               const float* __restrict__ al_all, const float* __restrict__ ar_all,
               float* __restrict__ el_all, float* __restrict__ er_all,
               const float* __restrict__ tvec_all, const float* __restrict__ bvec_all,
               const f16* __restrict__ W12Tg, const float* __restrict__ bp,
               int ldc)
{
  __shared__ alignas(16) f16 Bs[256][264];                  // 135 KB
  __shared__ alignas(16) f16 W12s[MODE ? 256 : 1][MODE ? 40 : 8];

  const int tid = threadIdx.x;
  const int et = blockIdx.y;
  const int lane = tid & 63, wv = tid >> 6;
  const int l15 = lane & 15, lq = lane >> 4;
  const int wr = wv >> 1, wc = wv & 1;
  const int bm = blockIdx.x * 128;
  const int cb = wc * 128;

  const f16* A = (MODE == 0) ? Abase : (Abase + (size_t)et * M * 256);
  const f16* BT = (MODE == 0) ? (BTbase + (size_t)et * 65536) : BTbase;

#pragma unroll
  for (int i = 0; i < 16; ++i) {
    int seg = tid + i * 512;
    int row = seg >> 5;
    int cs = (seg & 31) * 8;
    *(uint4*)&Bs[row][cs] = *(const uint4*)&BT[(size_t)row * 256 + cs];
  }
  if (MODE == 1) {
    for (int i = tid; i < 2560; i += 512)
      ((uint2*)&W12s[0][0])[i] = ((const uint2*)W12Tg)[i];
  }
  __syncthreads();

  const int r0 = bm + wr * 32 + l15;
  const int r1 = r0 + 16;
  const bool ok0 = r0 < M, ok1 = r1 < M;
  const f16* Arow0 = A + (size_t)r0 * 256;
  const f16* Arow1 = A + (size_t)r1 * 256;

  f32x4 acc[2][8] = {};

#pragma unroll
  for (int k0 = 0; k0 < 256; k0 += 32) {
    int ko = k0 + lq * 8;
    f16x8 a0 = {0, 0, 0, 0, 0, 0, 0, 0};
    f16x8 a1 = {0, 0, 0, 0, 0, 0, 0, 0};
    if (ok0) a0 = *(const f16x8*)(Arow0 + ko);
    if (ok1) a1 = *(const f16x8*)(Arow1 + ko);
#pragma unroll
    for (int nf = 0; nf < 8; ++nf) {
      f16x8 bf = *(const f16x8*)&Bs[cb + nf * 16 + l15][ko];
      acc[0][nf] = __builtin_amdgcn_mfma_f32_16x16x32_f16(a0, bf, acc[0][nf], 0, 0, 0);
      acc[1][nf] = __builtin_amdgcn_mfma_f32_16x16x32_f16(a1, bf, acc[1][nf], 0, 0, 0);
    }
  }

  if (MODE == 0) {
    f16* Ch = Chbase + (size_t)et * M * 256;
    float* el = el_all + (size_t)et * M * 4;
    float* er = er_all + (size_t)et * M * 4;
    const float* al = al_all + et * 256;
    const float* ar = ar_all + et * 256;
    float alv[8], arv[8];
#pragma unroll
    for (int nf = 0; nf < 8; ++nf) {
      alv[nf] = al[cb + nf * 16 + l15];
      arv[nf] = ar[cb + nf * 16 + l15];
    }
#pragma unroll
    for (int m = 0; m < 2; ++m)
#pragma unroll
      for (int i = 0; i < 4; ++i) {
        int row = bm + wr * 32 + m * 16 + lq * 4 + i;
        float peA = 0.f, prA = 0.f, peB = 0.f, prB = 0.f;
#pragma unroll
        for (int nf = 0; nf < 4; ++nf) {
          peA = fmaf(acc[m][nf][i], alv[nf], peA);
          prA = fmaf(acc[m][nf][i], arv[nf], prA);
          peB = fmaf(acc[m][nf + 4][i], alv[nf + 4], peB);
          prB = fmaf(acc[m][nf + 4][i], arv[nf + 4], prB);
        }
#pragma unroll
        for (int o = 8; o >= 1; o >>= 1) {
          peA += __shfl_xor(peA, o, 64);
          prA += __shfl_xor(prA, o, 64);
          peB += __shfl_xor(peB, o, 64);
          prB += __shfl_xor(prB, o, 64);
        }
        if (row < M) {
          if (l15 == 0) {
            int hA = wc * 2;
            el[row * 4 + hA] = peA;     er[row * 4 + hA] = prA;
            el[row * 4 + hA + 1] = peB; er[row * 4 + hA + 1] = prB;
          }
#pragma unroll
          for (int nf = 0; nf < 8; ++nf)
            Ch[(size_t)row * 256 + cb + nf * 16 + l15] = (f16)acc[m][nf][i];
        }
      }
  } else {
    const float* tvec = tvec_all + (size_t)et * M * 8;
    const float* bvec = bvec_all + (size_t)et * M * 8;
    const int coff = et * 256;
    // rank-8 correction via one MFMA per (m, nf): A-frag = [t(8), bo(8), 0(16)]
#pragma unroll
    for (int m = 0; m < 2; ++m) {
      int arow = bm + wr * 32 + m * 16 + l15;
      f16x8 af = {0, 0, 0, 0, 0, 0, 0, 0};
      if (arow < M && lq < 2) {
        const float* srcp = (lq == 0) ? &tvec[(size_t)arow * 8] : &bvec[(size_t)arow * 8];
        float4 x0 = *(const float4*)srcp;
        float4 x1 = *(const float4*)(srcp + 4);
        af[0] = (f16)x0.x; af[1] = (f16)x0.y; af[2] = (f16)x0.z; af[3] = (f16)x0.w;
        af[4] = (f16)x1.x; af[5] = (f16)x1.y; af[6] = (f16)x1.z; af[7] = (f16)x1.w;
      }
#pragma unroll
      for (int nf = 0; nf < 8; ++nf) {
        f16x8 bf2 = *(const f16x8*)&W12s[cb + nf * 16 + l15][lq * 8];
        acc[m][nf] = __builtin_amdgcn_mfma_f32_16x16x32_f16(af, bf2, acc[m][nf], 0, 0, 0);
      }
    }
    float bpv[8];
#pragma unroll
    for (int nf = 0; nf < 8; ++nf) bpv[nf] = bp[cb + nf * 16 + l15];
#pragma unroll
    for (int m = 0; m < 2; ++m)
#pragma unroll
      for (int i = 0; i < 4; ++i) {
        int row = bm + wr * 32 + m * 16 + lq * 4 + i;
        if (row >= M) continue;
#pragma unroll
        for (int nf = 0; nf < 8; ++nf)
          Cf[(size_t)row * ldc + coff + cb + nf * 16 + l15] = acc[m][nf][i] + bpv[nf];
      }
  }
}

// ============== CSR build pass 1: LDS histogram + per-edge local rank ==============
__global__ __launch_bounds__(512)
void hist_kernel(const int* __restrict__ d0, const int* __restrict__ d1,
                 const int* __restrict__ d2, unsigned short* __restrict__ ghist,
                 unsigned short* __restrict__ rank16)
{
  __shared__ unsigned int h32[N_NODES / 2];
  int et = blockIdx.y, b = blockIdx.x, tid = threadIdx.x;
  const int* dst = (et == 0) ? d0 : (et == 1) ? d1 : d2;
  for (int i = tid; i < N_NODES / 2; i += 512) h32[i] = 0u;
  __syncthreads();
  int e0 = b * CHUNK;
  for (int i = tid; i < CHUNK; i += 512) {
    int e = e0 + i;
    int d = dst[e];
    unsigned int sh = (d & 1) * 16;
    unsigned int old = atomicAdd(&h32[d >> 1], 1u << sh);
    rank16[(size_t)et * N_EDGES + e] = (unsigned short)((old >> sh) & 0xFFFFu);
  }
  __syncthreads();
  unsigned short* gh = ghist + ((size_t)(et * NB + b)) * N_NODES;
  for (int d = tid; d < N_NODES; d += 512)
    gh[d] = (unsigned short)((h32[d >> 1] >> ((d & 1) * 16)) & 0xFFFFu);
}

// ============== pass 2: per-dst exclusive prefix over NB blocks + totals ==============
__global__ __launch_bounds__(256)
void blockpfx_kernel(unsigned short* __restrict__ ghist, int* __restrict__ counts)
{
  int d = blockIdx.x * 256 + threadIdx.x;
  int et = blockIdx.y;
  if (d >= N_NODES) return;
  int running = 0;
#pragma unroll
  for (int b = 0; b < NB; ++b) {
    size_t idx = ((size_t)(et * NB + b)) * N_NODES + d;
    int v = ghist[idx];
    ghist[idx] = (unsigned short)running;
    running += v;
  }
  counts[et * N_NODES + d] = running;
}

// ============== batched scan (blockIdx.x = etype) ==============
__global__ __launch_bounds__(1024)
void scan_kernel(int* __restrict__ cc_all, int* __restrict__ off_all, int n, int total)
{
  int et = blockIdx.x;
  int* cc = cc_all + (size_t)et * n;
  int* off = off_all + (size_t)et * (n + 1);
  __shared__ int wsum[16];
  __shared__ int woff[16];
  __shared__ int s_carry, s_chunk;
  int tid = threadIdx.x;
  int lane = tid & 63, wid = tid >> 6;
  if (tid == 0) s_carry = 0;
  __syncthreads();
  for (int base = 0; base < n; base += 1024) {
    int i = base + tid;
    int v = (i < n) ? cc[i] : 0;
    int x = v;
#pragma unroll
    for (int s = 1; s < 64; s <<= 1) {
      int y = __shfl_up(x, s, 64);
      if (lane >= s) x += y;
    }
    if (lane == 63) wsum[wid] = x;
    __syncthreads();
    if (wid == 0 && lane < 16) {
      int ws_ = wsum[lane];
      int xx = ws_;
#pragma unroll
      for (int s = 1; s < 16; s <<= 1) {
        int y = __shfl_up(xx, s, 64);
        if (lane >= s) xx += y;
      }
      woff[lane] = xx - ws_;
      if (lane == 15) s_chunk = xx;
    }
    __syncthreads();
    int excl = s_carry + woff[wid] + (x - v);
    if (i < n) { off[i] = excl; cc[i] = excl; }
    __syncthreads();
    if (tid == 0) s_carry += s_chunk;
    __syncthreads();
  }
  if (tid == 0) off[n] = total;
}

// ============== pass 4: place packed payload src|f16(ew)<<16 (single 4B scatter) ==============
__global__ __launch_bounds__(256)
void place_kernel(const int* __restrict__ d0, const int* __restrict__ d1,
                  const int* __restrict__ d2,
                  const int* __restrict__ s0, const int* __restrict__ s1,
                  const int* __restrict__ s2,
                  const float* __restrict__ w0, const float* __restrict__ w1,
                  const float* __restrict__ w2,
                  const int* __restrict__ off, const unsigned short* __restrict__ ghist,
                  const unsigned short* __restrict__ rank16,
                  unsigned int* __restrict__ csr_pay)
{
  int e = blockIdx.x * 256 + threadIdx.x;
  if (e >= N_EDGES) return;
  int et = blockIdx.y;
  const int* dst = (et == 0) ? d0 : (et == 1) ? d1 : d2;
  const int* src = (et == 0) ? s0 : (et == 1) ? s1 : s2;
  const float* ew = (et == 0) ? w0 : (et == 1) ? w1 : w2;
  int d = dst[e];
  int b = e / CHUNK;
  int pos = off[et * (N_NODES + 1) + d]
          + (int)ghist[((size_t)(et * NB + b)) * N_NODES + d]
          + (int)rank16[(size_t)et * N_EDGES + e];
  unsigned short hw = __half_as_ushort(__float2half_rn(ew[e]));
  csr_pay[(size_t)et * N_EDGES + pos] = (unsigned int)src[e] | ((unsigned int)hw << 16);
}

// ============== column-tiled aggregation: grid (938, 4, 3); z = etype ==============
__global__ __launch_bounds__(512)
void aggregate_kernel(const int* __restrict__ off_all, const unsigned int* __restrict__ pay_all,
                      const float* __restrict__ el_all, const float* __restrict__ er_all,
                      const __half* __restrict__ feat_all, const float* __restrict__ b_all,
                      __half* __restrict__ gat_all, int n_nodes)
{
  int tid = threadIdx.x;
  int lane = tid & 63, wv = tid >> 6;     // 8 waves
  int lg = lane >> 4, lc = lane & 15;     // node-sub, col-group
  int cp = blockIdx.y;                    // col pass == head
  int et = blockIdx.z;
  int n = blockIdx.x * 32 + wv * 4 + lg;
  if (n >= n_nodes) return;
  int cbase = cp * 64 + lc * 4;

  const int* off = off_all + (size_t)et * (n_nodes + 1);
  const unsigned int* csr_pay = pay_all + (size_t)et * N_EDGES;
  const float* el = el_all + (size_t)et * n_nodes * 4;
  const __half* feat = feat_all + (size_t)et * n_nodes * 256;
  const float* bias = b_all + et * 256;

  int e0 = off[n], e1 = off[n + 1];
  float ern = er_all[((size_t)et * n_nodes + n) * 4 + cp];
  float ac0 = 0.f, ac1 = 0.f, ac2 = 0.f, ac3 = 0.f, dn = 0.f;

  int e = e0;
  for (; e + 3 < e1; e += 4) {
    unsigned int p0 = csr_pay[e], p1 = csr_pay[e + 1];
    unsigned int p2 = csr_pay[e + 2], p3 = csr_pay[e + 3];
    int s0 = (int)(p0 & 0xFFFFu), s1 = (int)(p1 & 0xFFFFu);
    int s2 = (int)(p2 & 0xFFFFu), s3 = (int)(p3 & 0xFFFFu);
    float v0 = el[s0 * 4 + cp] + ern; v0 = v0 > 0.f ? v0 : 0.2f * v0;
    float v1 = el[s1 * 4 + cp] + ern; v1 = v1 > 0.f ? v1 : 0.2f * v1;
    float v2 = el[s2 * 4 + cp] + ern; v2 = v2 > 0.f ? v2 : 0.2f * v2;
    float v3 = el[s3 * 4 + cp] + ern; v3 = v3 > 0.f ? v3 : 0.2f * v3;
    float x0 = __expf(v0), x1 = __expf(v1), x2 = __expf(v2), x3 = __expf(v3);
    dn += x0 + x1 + x2 + x3;
    float c0 = x0 * __half2float(__ushort_as_half((unsigned short)(p0 >> 16)));
    float c1 = x1 * __half2float(__ushort_as_half((unsigned short)(p1 >> 16)));
    float c2 = x2 * __half2float(__ushort_as_half((unsigned short)(p2 >> 16)));
    float c3 = x3 * __half2float(__ushort_as_half((unsigned short)(p3 >> 16)));
    uint2 u0 = *(const uint2*)(feat + (size_t)s0 * 256 + cbase);
    uint2 u1 = *(const uint2*)(feat + (size_t)s1 * 256 + cbase);
    uint2 u2 = *(const uint2*)(feat + (size_t)s2 * 256 + cbase);
    uint2 u3 = *(const uint2*)(feat + (size_t)s3 * 256 + cbase);
    float2 A01 = __half22float2(*(__half2*)&u0.x), A23 = __half22float2(*(__half2*)&u0.y);
    float2 B01 = __half22float2(*(__half2*)&u1.x), B23 = __half22float2(*(__half2*)&u1.y);
    float2 C01 = __half22float2(*(__half2*)&u2.x), C23 = __half22float2(*(__half2*)&u2.y);
    float2 D01 = __half22float2(*(__half2*)&u3.x), D23 = __half22float2(*(__half2*)&u3.y);
    ac0 = fmaf(c0, A01.x, ac0); ac1 = fmaf(c0, A01.y, ac1);
    ac2 = fmaf(c0, A23.x, ac2); ac3 = fmaf(c0, A23.y, ac3);
    ac0 = fmaf(c1, B01.x, ac0); ac1 = fmaf(c1, B01.y, ac1);
    ac2 = fmaf(c1, B23.x, ac2); ac3 = fmaf(c1, B23.y, ac3);
    ac0 = fmaf(c2, C01.x, ac0); ac1 = fmaf(c2, C01.y, ac1);
    ac2 = fmaf(c2, C23.x, ac2); ac3 = fmaf(c2, C23.y, ac3);
    ac0 = fmaf(c3, D01.x, ac0); ac1 = fmaf(c3, D01.y, ac1);
    ac2 = fmaf(c3, D23.x, ac2); ac3 = fmaf(c3, D23.y, ac3);
  }
  for (; e < e1; ++e) {
    unsigned int p0 = csr_pay[e];
    int s0 = (int)(p0 & 0xFFFFu);
    float v0 = el[s0 * 4 + cp] + ern; v0 = v0 > 0.f ? v0 : 0.2f * v0;
    float x0 = __expf(v0);
    dn += x0;
    float c0 = x0 * __half2float(__ushort_as_half((unsigned short)(p0 >> 16)));
    uint2 u0 = *(const uint2*)(feat + (size_t)s0 * 256 + cbase);
    float2 A01 = __half22float2(*(__half2*)&u0.x), A23 = __half22float2(*(__half2*)&u0.y);
    ac0 = fmaf(c0, A01.x, ac0); ac1 = fmaf(c0, A01.y, ac1);
    ac2 = fmaf(c0, A23.x, ac2); ac3 = fmaf(c0, A23.y, ac3);
  }

  float invd = (dn != 0.f) ? 1.f / dn : 0.f;
  float4 bv = *(const float4*)&bias[cbase];
  __half2 h01 = __floats2half2_rn(ac0 * invd + bv.x, ac1 * invd + bv.y);
  __half2 h23 = __floats2half2_rn(ac2 * invd + bv.z, ac3 * invd + bv.w);
  uint2 st;
  st.x = *(unsigned int*)&h01;
  st.y = *(unsigned int*)&h23;
  *(uint2*)&gat_all[((size_t)et * n_nodes + n) * 256 + cbase] = st;
}

// ============== [gt|gb] = gat @ W16 via MFMA, all 3N rows in one launch ==============
__global__ __launch_bounds__(256)
void project_mfma_kernel(const f16* __restrict__ gat, const f16* __restrict__ W16T,
                         float* __restrict__ gt, float* __restrict__ gb, int M)
{
  __shared__ alignas(16) f16 Ws[16][256];   // 8 KB
  int tid = threadIdx.x;
  for (int i = tid; i < 512; i += 256)
    ((uint4*)&Ws[0][0])[i] = ((const uint4*)W16T)[i];
  __syncthreads();

  int lane = tid & 63, wv = tid >> 6;
  int l15 = lane & 15, lq = lane >> 4;
  int bm = blockIdx.x * 128 + wv * 32;
  int r0 = bm + l15, r1 = r0 + 16;
  bool ok0 = r0 < M, ok1 = r1 < M;

  f32x4 acc[2] = {};
#pragma unroll
  for (int k0 = 0; k0 < 256; k0 += 32) {
    int ko = k0 + lq * 8;
    f16x8 a0 = {0, 0, 0, 0, 0, 0, 0, 0};
    f16x8 a1 = {0, 0, 0, 0, 0, 0, 0, 0};
    if (ok0) a0 = *(const f16x8*)(gat + (size_t)r0 * 256 + ko);
    if (ok1) a1 = *(const f16x8*)(gat + (size_t)r1 * 256 + ko);
    f16x8 bf = *(const f16x8*)&Ws[l15][ko];
    acc[0] = __builtin_amdgcn_mfma_f32_16x16x32_f16(a0, bf, acc[0], 0, 0, 0);
    acc[1] = __builtin_amdgcn_mfma_f32_16x16x32_f16(a1, bf, acc[1], 0, 0, 0);
  }
#pragma unroll
  for (int m = 0; m < 2; ++m)
#pragma unroll
    for (int i = 0; i < 4; ++i) {
      int row = bm + m * 16 + lq * 4 + i;
      if (row >= M) continue;
      float v = acc[m][i];
      if (l15 < 8) gt[(size_t)row * 8 + l15] = v;
      else         gb[(size_t)row * 8 + (l15 - 8)] = v;
    }
}

// ============== enhance: wave-per-node, batched over et (blockIdx.y) ==============
__global__ __launch_bounds__(256)
void enhance_pool_kernel(const int* __restrict__ ni0, const int* __restrict__ ni1,
                         const int* __restrict__ ni2,
                         const float* __restrict__ nw0, const float* __restrict__ nw1,
                         const float* __restrict__ nw2,
                         const float* __restrict__ gt_all, const float* __restrict__ gb_all,
                         const float* __restrict__ bt, const float* __restrict__ bb,
                         float* __restrict__ tvec_all, float* __restrict__ bvec_all, int n_nodes)
{
  int n = (blockIdx.x * 256 + threadIdx.x) >> 6;
  int lane = threadIdx.x & 63;
  if (n >= n_nodes) return;
  int et = blockIdx.y;
  const int* nbr_idx = (et == 0) ? ni0 : (et == 1) ? ni1 : ni2;
  const float* nbr_w = (et == 0) ? nw0 : (et == 1) ? nw1 : nw2;
  const float* gt = gt_all + (size_t)et * n_nodes * 8;
  const float* gb = gb_all + (size_t)et * n_nodes * 8;
  float* tvec = tvec_all + (size_t)et * n_nodes * 8;
  float* bvec = bvec_all + (size_t)et * n_nodes * 8;
  const int l16 = lane & 15;

  float w = nbr_w[(size_t)n * 16 + l16];
  int idx = nbr_idx[(size_t)n * 16 + l16];

  int rhi = 0, rlo = 0;
#pragma unroll
  for (int i = 0; i < 16; ++i) {
    float wi = __shfl(w, i, 64);
    rhi += (wi > w) || (wi == w && i < l16);
    rlo += (wi < w) || (wi == w && i < l16);
  }

  int rows[7];
#pragma unroll
  for (int q = 0; q < 5; ++q) {
    unsigned long long m = __ballot(lane < 16 && rhi == q);
    rows[q] = __shfl(idx, __ffsll(m) - 1, 64);
  }
#pragma unroll
  for (int q = 0; q < 2; ++q) {
    unsigned long long m = __ballot(lane < 16 && rlo == q);
    rows[5 + q] = __shfl(idx, __ffsll(m) - 1, 64);
  }

  int j = lane & 7;
  if (lane < 8) {
    float s = 0.f;
#pragma unroll
    for (int q = 0; q < 5; ++q) s += gt[(size_t)rows[q] * 8 + j];
    tvec[(size_t)n * 8 + j] = s * 0.2f + bt[j];
  } else if (lane < 16) {
    float s = gb[(size_t)rows[5] * 8 + j] + gb[(size_t)rows[6] * 8 + j];
    bvec[(size_t)n * 8 + j] = s * 0.5f + bb[j];
  }
}

extern "C" void kernel_launch(void* const* d_in, const int* in_sizes, int n_in,
                              void* d_out, int out_size, void* d_ws, size_t ws_size,
                              hipStream_t stream)
{
  const int N_ = N_NODES;
  const int E_ = N_EDGES;

  const float* h = (const float*)d_in[0];
  const float* Wt = (const float*)d_in[28];
  const float* bt = (const float*)d_in[29];
  const float* Wb = (const float*)d_in[30];
  const float* bb = (const float*)d_in[31];
  const float* Wp = (const float*)d_in[32];
  const float* bp = (const float*)d_in[33];
  float* out = (float*)d_out;

  char* wsb = (char*)d_ws;
  size_t o = 0;
  auto alloc = [&](size_t bytes) -> void* {
    void* p = wsb + o;
    o = (o + bytes + 255) & ~(size_t)255;
    return p;
  };
  f16*  hf    = (f16*)alloc((size_t)N_ * 256 * 2);
  f16*  feat  = (f16*)alloc((size_t)3 * N_ * 256 * 2);   // 46 MB
  f16*  gat   = (f16*)alloc((size_t)3 * N_ * 256 * 2);   // 46 MB
  f16*  WT    = (f16*)alloc((size_t)4 * 256 * 256 * 2);  // 3x W + WpT
  f16*  W12T  = (f16*)alloc((size_t)256 * 40 * 2);
  f16*  W16T  = (f16*)alloc((size_t)16 * 256 * 2);
  float* al_all = (float*)alloc((size_t)3 * 256 * 4);
  float* ar_all = (float*)alloc((size_t)3 * 256 * 4);
  float* b_all  = (float*)alloc((size_t)3 * 256 * 4);
  float* el     = (float*)alloc((size_t)3 * N_ * 4 * 4);
  float* er     = (float*)alloc((size_t)3 * N_ * 4 * 4);
  float* gt     = (float*)alloc((size_t)3 * N_ * 8 * 4);
  float* gb     = (float*)alloc((size_t)3 * N_ * 8 * 4);
  float* tvec   = (float*)alloc((size_t)3 * N_ * 8 * 4);
  float* bvec   = (float*)alloc((size_t)3 * N_ * 8 * 4);
  int*   off    = (int*)alloc((size_t)3 * (N_ + 1) * 4);
  int*   counts = (int*)alloc((size_t)3 * N_ * 4);
  unsigned short* ghist = (unsigned short*)alloc((size_t)3 * NB * N_ * 2);
  unsigned short* rank16 = (unsigned short*)alloc((size_t)3 * E_ * 2);
  unsigned int* csr_pay = (unsigned int*)alloc((size_t)3 * E_ * 4);
  (void)ws_size; (void)in_sizes; (void)n_in; (void)out_size;

  const int row_blocks = (N_ + 127) / 128;  // 235
  const int edge_blocks = (E_ + 255) / 256; // 1875
  const int wave_blocks = (N_ + 3) / 4;     // 7500 (enhance)
  const int agg_blocks = (N_ + 31) / 32;    // 938 (aggregate)
  const int prj_blocks = (3 * N_ + 127) / 128;  // 704 (project, all etypes)

  const int* d_dst0 = (const int*)d_in[1 + 0 * 9 + 1];
  const int* d_dst1 = (const int*)d_in[1 + 1 * 9 + 1];
  const int* d_dst2 = (const int*)d_in[1 + 2 * 9 + 1];
  const int* d_src0 = (const int*)d_in[1 + 0 * 9 + 0];
  const int* d_src1 = (const int*)d_in[1 + 1 * 9 + 0];
  const int* d_src2 = (const int*)d_in[1 + 2 * 9 + 0];
  const float* d_ew0 = (const float*)d_in[1 + 0 * 9 + 2];
  const float* d_ew1 = (const float*)d_in[1 + 1 * 9 + 2];
  const float* d_ew2 = (const float*)d_in[1 + 2 * 9 + 2];

  // one-time conversions (independent of CSR build)
  convert_h_kernel<<<(N_ * 256 / 8 + 255) / 256, 256, 0, stream>>>(h, hf, N_ * 256 / 8);
  transpose_w_kernel<<<dim3(256, 4), 256, 0, stream>>>(
      (const float*)d_in[1 + 0 * 9 + 5], (const float*)d_in[1 + 1 * 9 + 5],
      (const float*)d_in[1 + 2 * 9 + 5], Wp, WT);
  w12_kernel<<<(256 * 40 + 255) / 256, 256, 0, stream>>>(Wp, W12T);
  w16_kernel<<<16, 256, 0, stream>>>(Wt, Wb, W16T);
  pack_params_kernel<<<3, 256, 0, stream>>>(
      (const float*)d_in[1 + 0 * 9 + 6], (const float*)d_in[1 + 1 * 9 + 6],
      (const float*)d_in[1 + 2 * 9 + 6],
      (const float*)d_in[1 + 0 * 9 + 7], (const float*)d_in[1 + 1 * 9 + 7],
      (const float*)d_in[1 + 2 * 9 + 7],
      (const float*)d_in[1 + 0 * 9 + 8], (const float*)d_in[1 + 1 * 9 + 8],
      (const float*)d_in[1 + 2 * 9 + 8],
      al_all, ar_all, b_all);
  f16* WpT = WT + (size_t)3 * 65536;

  // atomic-free CSR build (batched over etypes)
  hist_kernel<<<dim3(NB, 3), 512, 0, stream>>>(d_dst0, d_dst1, d_dst2, ghist, rank16);
  blockpfx_kernel<<<dim3((N_ + 255) / 256, 3), 256, 0, stream>>>(ghist, counts);
  scan_kernel<<<3, 1024, 0, stream>>>(counts, off, N_, E_);
  place_kernel<<<dim3(edge_blocks, 3), 256, 0, stream>>>(
      d_dst0, d_dst1, d_dst2, d_src0, d_src1, d_src2, d_ew0, d_ew1, d_ew2,
      off, ghist, rank16, csr_pay);

  // fully batched pipeline: each stage covers all 3 etypes
  gemm_mfma<0><<<dim3(row_blocks, 3), 512, 0, stream>>>(
      hf, WT, feat, nullptr, N_, al_all, ar_all, el, er,
      nullptr, nullptr, nullptr, nullptr, 256);

  aggregate_kernel<<<dim3(agg_blocks, 4, 3), 512, 0, stream>>>(
      off, csr_pay, el, er, (const __half*)feat, b_all, (__half*)gat, N_);

  project_mfma_kernel<<<prj_blocks, 256, 0, stream>>>(
      gat, W16T, gt, gb, 3 * N_);

  enhance_pool_kernel<<<dim3(wave_blocks, 3), 256, 0, stream>>>(
      (const int*)d_in[1 + 0 * 9 + 3], (const int*)d_in[1 + 1 * 9 + 3],
      (const int*)d_in[1 + 2 * 9 + 3],
      (const float*)d_in[1 + 0 * 9 + 4], (const float*)d_in[1 + 1 * 9 + 4],
      (const float*)d_in[1 + 2 * 9 + 4],
      gt, gb, bt, bb, tvec, bvec, N_);

  gemm_mfma<1><<<dim3(row_blocks, 3), 512, 0, stream>>>(
      gat, WpT, nullptr, out, N_, nullptr, nullptr, nullptr, nullptr,
      tvec, bvec, W12T, bp, 768);
}